// Round 18
// baseline (296.132 us; speedup 1.0000x reference)
//
#include <hip/hip_runtime.h>
#include <hip/hip_fp16.h>

// ---------------------------------------------------------------------------
// GNN_20237885899323: 2-layer GCN + mean-pool + MLP head, fp32 compute.
// Round 18: r17 post-mortem -- poolhead regressed because dropping the wcol
// VGPR cache put a GLOBAL w2 load on every FMA (load-issue bound, VALU 14%).
// Rebuild with each piece justified: w2 staged in LDS once (16KB, stride-1
// conflict-free), 4 independent FMA chains (r15's ILP lever), 512 threads
// (8 waves TLP). Aggs + CSR identical to r16 (249.2us anchor).
// ---------------------------------------------------------------------------

#define NBMAX 512
#define BCAP 12288
#define CAPL 10240

// pass A: bin edges by dst>>8; entry = (dst&255)<<24 | src.
// bcur[b] is a running COUNT (zeroed before launch). 8192-edge chunks so each
// (block,bucket) burst is ~16 entries = one full 64B line, one writer/line.
__global__ void k_passA(const int* __restrict__ ei, int* __restrict__ bcur,
                        unsigned int* __restrict__ pairBuf, int E) {
    const int T = 256, EPT = 32, CHUNK = T * EPT;  // 8192 edges/block
    __shared__ int dLds[CHUNK];
    __shared__ int h[NBMAX];
    __shared__ int base[NBMAX];
    int chunk = blockIdx.x * CHUNK;
    int t = threadIdx.x;
    h[t] = 0; h[t + 256] = 0;
    __syncthreads();
    int nE = min(E - chunk, CHUNK);
    for (int i = t; i < nE; i += T) {
        int d = ei[E + chunk + i];
        dLds[i] = d;
        atomicAdd(&h[d >> 8], 1);
    }
    __syncthreads();
    for (int bb = t; bb < NBMAX; bb += T) {
        int c = h[bb];
        base[bb] = c > 0 ? atomicAdd(&bcur[bb], c) : 0;  // reserve [base, base+c)
        h[bb] = 0;  // becomes local cursor
    }
    __syncthreads();
    for (int i = t; i < nE; i += T) {
        int s = ei[chunk + i];
        int d = dLds[i];
        int bb = d >> 8;
        int pos = base[bb] + atomicAdd(&h[bb], 1);
        pairBuf[(size_t)bb * BCAP + pos] = ((unsigned int)(d & 255) << 24) | (unsigned int)s;
    }
}

// pass B: per-bucket counting sort -> rowPtr, dis, srcIdx, p={x0,x1,dis,0}
__global__ void k_passB(const int* __restrict__ bcur,
                        const unsigned int* __restrict__ pairBuf,
                        int* __restrict__ rowPtr, float* __restrict__ dis,
                        int* __restrict__ srcIdx, const float* __restrict__ x,
                        float4* __restrict__ p, int N, int E) {
    __shared__ unsigned int eLds[CAPL];
    __shared__ int hist[256];
    __shared__ int scan[256];
    int b = blockIdx.x;
    int t = threadIdx.x;  // 256
    int count = bcur[b];
    const unsigned int* src = pairBuf + (size_t)b * BCAP;
    // gbase = sum of bucket counts below b (redundant per-block reduce)
    int part = 0;
    for (int i = t; i < b; i += 256) part += bcur[i];
    scan[t] = part;
    __syncthreads();
    for (int o = 128; o > 0; o >>= 1) {
        if (t < o) scan[t] += scan[t + o];
        __syncthreads();
    }
    int gbase = scan[0];
    __syncthreads();
    hist[t] = 0;
    int nStage = min(count, CAPL);
    for (int i = t; i < nStage; i += 256) eLds[i] = __builtin_nontemporal_load(src + i);
    __syncthreads();
    for (int i = t; i < nStage; i += 256) atomicAdd(&hist[eLds[i] >> 24], 1);
    for (int i = CAPL + t; i < count; i += 256)
        atomicAdd(&hist[__builtin_nontemporal_load(src + i) >> 24], 1);
    __syncthreads();
    int c = hist[t];
    scan[t] = c;
    __syncthreads();
    for (int o = 1; o < 256; o <<= 1) {
        int v = (t >= o) ? scan[t - o] : 0;
        __syncthreads();
        scan[t] += v;
        __syncthreads();
    }
    int excl = scan[t] - c;
    int node = (b << 8) + t;
    float dval = rsqrtf((float)c + 1.0f);  // +1 self loop
    if (node < N) {
        rowPtr[node] = gbase + excl;
        dis[node] = dval;
        float4 pv;
        pv.x = x[2 * node]; pv.y = x[2 * node + 1]; pv.z = dval; pv.w = 0.f;
        p[node] = pv;
        if (node == N - 1) rowPtr[N] = E;
    }
    hist[t] = excl;
    __syncthreads();
    for (int i = t; i < nStage; i += 256) {
        unsigned int e = eLds[i];
        int pos = atomicAdd(&hist[e >> 24], 1);
        srcIdx[gbase + pos] = (int)(e & 0xFFFFFFu);  // cached: clustered, L2 merges
    }
    for (int i = CAPL + t; i < count; i += 256) {
        unsigned int e = __builtin_nontemporal_load(src + i);
        int pos = atomicAdd(&hist[e >> 24], 1);
        srcIdx[gbase + pos] = (int)(e & 0xFFFFFFu);
    }
}

// layer 1, TWO nodes per wave: gather p[src] (16B, L2-resident), recompute
// h~0 in-register; two independent chains; dual butterfly; fused @w1 -> fp16.
__global__ void k_agg32x2(const int* __restrict__ rowPtr, const int* __restrict__ srcIdx,
                          const float4* __restrict__ p, const float* __restrict__ wn,
                          const float* __restrict__ bn, const float* __restrict__ w1,
                          const float* __restrict__ bb1, __half* __restrict__ hOut, int N) {
    constexpr int RPI = 8, U = 4, CH = RPI * U;  // 32 slots per node per iter
    int wid = (blockIdx.x * blockDim.x + threadIdx.x) >> 6;
    int n0 = 2 * wid;
    if (n0 >= N) return;
    int n1 = n0 + 1;
    bool has1 = (n1 < N);
    int lane = threadIdx.x & 63;
    int q = lane & 7;   // feature quad: f = 4q..4q+3
    int r = lane >> 3;  // row group 0..7
    float w0c[4], w1c[4], bnv[4];
#pragma unroll
    for (int j = 0; j < 4; ++j) {
        w0c[j] = wn[4 * q + j];
        w1c[j] = wn[32 + 4 * q + j];
        bnv[j] = bn[4 * q + j];
    }
    float4 pd0 = p[n0];
    float4 pd1 = p[has1 ? n1 : n0];
    float a0[4] = {0.f, 0.f, 0.f, 0.f};
    float a1[4] = {0.f, 0.f, 0.f, 0.f};
    if (r == 0) {  // self loops
#pragma unroll
        for (int j = 0; j < 4; ++j) {
            float v0 = fmaf(pd0.x, w0c[j], fmaf(pd0.y, w1c[j], bnv[j]));
            a0[j] = fmaxf(v0, 0.f) * pd0.z;
            float v1 = fmaf(pd1.x, w0c[j], fmaf(pd1.y, w1c[j], bnv[j]));
            a1[j] = has1 ? fmaxf(v1, 0.f) * pd1.z : 0.f;
        }
    }
    // adjacent segments: 3 rowPtr loads cover both
    int b0 = rowPtr[n0];
    int e0 = rowPtr[n0 + 1];
    int e1 = has1 ? rowPtr[n0 + 2] : e0;
    int beg1 = e0;
    for (int base0 = b0, base1 = beg1; base0 < e0 || base1 < e1;
         base0 += CH, base1 += CH) {
        int s0[U], s1[U];
        float m0[U], m1[U];
#pragma unroll
        for (int u = 0; u < U; ++u) {
            int i0 = base0 + r + u * RPI;
            m0[u] = (i0 < e0) ? 1.f : 0.f;
            s0[u] = __builtin_nontemporal_load(srcIdx + ((e0 > b0) ? min(i0, e0 - 1) : 0));
            int i1 = base1 + r + u * RPI;
            m1[u] = (i1 < e1) ? 1.f : 0.f;
            s1[u] = __builtin_nontemporal_load(srcIdx + ((e1 > beg1) ? min(i1, e1 - 1) : 0));
        }
        float4 ps0[U], ps1[U];
#pragma unroll
        for (int u = 0; u < U; ++u) ps0[u] = p[s0[u]];
#pragma unroll
        for (int u = 0; u < U; ++u) ps1[u] = p[s1[u]];
#pragma unroll
        for (int u = 0; u < U; ++u) {
            float sc0 = ps0[u].z * m0[u];
            float sc1 = ps1[u].z * m1[u];
#pragma unroll
            for (int j = 0; j < 4; ++j) {
                float v0 = fmaf(ps0[u].x, w0c[j], fmaf(ps0[u].y, w1c[j], bnv[j]));
                a0[j] = fmaf(fmaxf(v0, 0.f), sc0, a0[j]);
                float v1 = fmaf(ps1[u].x, w0c[j], fmaf(ps1[u].y, w1c[j], bnv[j]));
                a1[j] = fmaf(fmaxf(v1, 0.f), sc1, a1[j]);
            }
        }
    }
    // dual butterfly reduce across row groups (two independent chains)
#pragma unroll
    for (int mk = 8; mk < 64; mk <<= 1) {
#pragma unroll
        for (int j = 0; j < 4; ++j) {
            a0[j] += __shfl_xor(a0[j], mk);
            a1[j] += __shfl_xor(a1[j], mk);
        }
    }
    // fused @w1 for both nodes; w1 column loaded once, reused
    int f = lane;
    float s0v = 0.f, s1v = 0.f;
#pragma unroll
    for (int q2 = 0; q2 < 8; ++q2) {
#pragma unroll
        for (int j = 0; j < 4; ++j) {
            float wv = w1[(4 * q2 + j) * 64 + f];
            s0v = fmaf(__shfl(a0[j], q2), wv, s0v);
            s1v = fmaf(__shfl(a1[j], q2), wv, s1v);
        }
    }
    float bias = bb1[f];
    float h0 = fmaxf(fmaf(pd0.z, s0v, bias), 0.f) * pd0.z;
    hOut[(size_t)n0 * 64 + f] = __float2half(h0);
    if (has1) {
        float h1 = fmaxf(fmaf(pd1.z, s1v, bias), 0.f) * pd1.z;
        hOut[(size_t)n1 * 64 + f] = __float2half(h1);
    }
}

// layer 2, TWO nodes per wave: fp16 128B-row gather, two independent chains
// (U=2 each), dual butterfly, both fp32 z-rows stored.
__global__ void k_agg64h2(const int* __restrict__ rowPtr, const int* __restrict__ srcIdx,
                          const __half* __restrict__ y, const float* __restrict__ dis,
                          float* __restrict__ z, int N) {
    constexpr int RPI = 8, U = 2, CH = RPI * U;  // 16 slots per node per iter
    int wid = (blockIdx.x * blockDim.x + threadIdx.x) >> 6;
    int n0 = 2 * wid;
    if (n0 >= N) return;
    int n1 = n0 + 1;
    bool has1 = (n1 < N);
    int lane = threadIdx.x & 63;
    int q = lane & 7;   // 16-byte chunk: features 8q..8q+7
    int r = lane >> 3;  // row group 0..7
    const float4* yq = (const float4*)y;  // one row = 8 float4 (64 halves)
    float acc0[8] = {0.f, 0.f, 0.f, 0.f, 0.f, 0.f, 0.f, 0.f};
    float acc1[8] = {0.f, 0.f, 0.f, 0.f, 0.f, 0.f, 0.f, 0.f};
    if (r == 0) {  // self rows
        float4 a = yq[(size_t)n0 * 8 + q];
        union { float4 f4; __half2 h2[4]; } cv; cv.f4 = a;
#pragma unroll
        for (int j = 0; j < 4; ++j) {
            float2 f = __half22float2(cv.h2[j]);
            acc0[2 * j] = f.x; acc0[2 * j + 1] = f.y;
        }
        if (has1) {
            float4 b = yq[(size_t)n1 * 8 + q];
            union { float4 f4; __half2 h2[4]; } cw; cw.f4 = b;
#pragma unroll
            for (int j = 0; j < 4; ++j) {
                float2 f = __half22float2(cw.h2[j]);
                acc1[2 * j] = f.x; acc1[2 * j + 1] = f.y;
            }
        }
    }
    int b0 = rowPtr[n0];
    int e0 = rowPtr[n0 + 1];
    int e1 = has1 ? rowPtr[n0 + 2] : e0;
    int beg1 = e0;
    for (int base0 = b0, base1 = beg1; base0 < e0 || base1 < e1;
         base0 += CH, base1 += CH) {
        int s0[U], s1[U];
        float m0[U], m1[U];
#pragma unroll
        for (int u = 0; u < U; ++u) {
            int i0 = base0 + r + u * RPI;
            m0[u] = (i0 < e0) ? 1.f : 0.f;
            s0[u] = __builtin_nontemporal_load(srcIdx + ((e0 > b0) ? min(i0, e0 - 1) : 0));
            int i1 = base1 + r + u * RPI;
            m1[u] = (i1 < e1) ? 1.f : 0.f;
            s1[u] = __builtin_nontemporal_load(srcIdx + ((e1 > beg1) ? min(i1, e1 - 1) : 0));
        }
#pragma unroll
        for (int u = 0; u < U; ++u) {
            float4 a = yq[(size_t)s0[u] * 8 + q];
            float4 b = yq[(size_t)s1[u] * 8 + q];
            union { float4 f4; __half2 h2[4]; } ca; ca.f4 = a;
            union { float4 f4; __half2 h2[4]; } cb; cb.f4 = b;
#pragma unroll
            for (int j = 0; j < 4; ++j) {
                float2 fa = __half22float2(ca.h2[j]);
                acc0[2 * j]     = fmaf(fa.x, m0[u], acc0[2 * j]);
                acc0[2 * j + 1] = fmaf(fa.y, m0[u], acc0[2 * j + 1]);
                float2 fb = __half22float2(cb.h2[j]);
                acc1[2 * j]     = fmaf(fb.x, m1[u], acc1[2 * j]);
                acc1[2 * j + 1] = fmaf(fb.y, m1[u], acc1[2 * j + 1]);
            }
        }
    }
    // dual butterfly reduce across the 8 row groups
#pragma unroll
    for (int mk = 8; mk < 64; mk <<= 1) {
#pragma unroll
        for (int j = 0; j < 8; ++j) {
            acc0[j] += __shfl_xor(acc0[j], mk);
            acc1[j] += __shfl_xor(acc1[j], mk);
        }
    }
    if (r == 0) {
        float dv0 = dis[n0];
        float4 o0 = {acc0[0] * dv0, acc0[1] * dv0, acc0[2] * dv0, acc0[3] * dv0};
        float4 o1 = {acc0[4] * dv0, acc0[5] * dv0, acc0[6] * dv0, acc0[7] * dv0};
        float4* zp0 = (float4*)(z + (size_t)n0 * 64 + q * 8);
        zp0[0] = o0;  // plain store: stays in L2 for poolhead
        zp0[1] = o1;
        if (has1) {
            float dv1 = dis[n1];
            float4 o2 = {acc1[0] * dv1, acc1[1] * dv1, acc1[2] * dv1, acc1[3] * dv1};
            float4 o3 = {acc1[4] * dv1, acc1[5] * dv1, acc1[6] * dv1, acc1[7] * dv1};
            float4* zp1 = (float4*)(z + (size_t)n1 * 64 + q * 8);
            zp1[0] = o2;
            zp1[1] = o3;
        }
    }
}

// block-per-graph (512 thr, 8 waves): w2 staged in LDS once; h2 computed with
// FOUR independent FMA chains (z-loads 4-deep in flight); mean; MLP head.
__global__ void k_poolhead(const float* __restrict__ z2, const float* __restrict__ w2,
                           const float* __restrict__ b2, const int* __restrict__ batch,
                           const float* __restrict__ wf1, const float* __restrict__ bf1,
                           const float* __restrict__ wf2, const float* __restrict__ bf2,
                           float* __restrict__ out, int N) {
    __shared__ float w2s[64 * 64];  // 16 KB, stride-1 per-lane reads: conflict-free
    __shared__ float red[8][64];
    __shared__ float pooled[64];
    __shared__ float gv[32];
    __shared__ int range[2];
    int g = blockIdx.x;
    int t = threadIdx.x;  // 512
    for (int i = t; i < 4096; i += 512) w2s[i] = w2[i];
    if (t < 2) {
        int target = g + t;
        int lo = 0, hi = N;
        while (lo < hi) {
            int mid = (lo + hi) >> 1;
            if (batch[mid] < target) lo = mid + 1; else hi = mid;
        }
        range[t] = lo;
    }
    __syncthreads();
    int s = range[0], e = range[1];
    int w = t >> 6, f = t & 63;  // 8 row-group waves, feature lane
    float bf = b2[f];
    float acc = 0.f;
    for (int n = s + w; n < e; n += 8) {
        const float4* zr = (const float4*)(z2 + (size_t)n * 64);
        float h0 = bf, h1 = 0.f, h2 = 0.f, h3 = 0.f;
#pragma unroll
        for (int kq = 0; kq < 4; ++kq) {
            float4 a = zr[kq];
            float4 b = zr[kq + 4];
            float4 c = zr[kq + 8];
            float4 d = zr[kq + 12];
            h0 = fmaf(a.x, w2s[(4 * kq + 0) * 64 + f], h0);
            h0 = fmaf(a.y, w2s[(4 * kq + 1) * 64 + f], h0);
            h0 = fmaf(a.z, w2s[(4 * kq + 2) * 64 + f], h0);
            h0 = fmaf(a.w, w2s[(4 * kq + 3) * 64 + f], h0);
            h1 = fmaf(b.x, w2s[(4 * (kq + 4) + 0) * 64 + f], h1);
            h1 = fmaf(b.y, w2s[(4 * (kq + 4) + 1) * 64 + f], h1);
            h1 = fmaf(b.z, w2s[(4 * (kq + 4) + 2) * 64 + f], h1);
            h1 = fmaf(b.w, w2s[(4 * (kq + 4) + 3) * 64 + f], h1);
            h2 = fmaf(c.x, w2s[(4 * (kq + 8) + 0) * 64 + f], h2);
            h2 = fmaf(c.y, w2s[(4 * (kq + 8) + 1) * 64 + f], h2);
            h2 = fmaf(c.z, w2s[(4 * (kq + 8) + 2) * 64 + f], h2);
            h2 = fmaf(c.w, w2s[(4 * (kq + 8) + 3) * 64 + f], h2);
            h3 = fmaf(d.x, w2s[(4 * (kq + 12) + 0) * 64 + f], h3);
            h3 = fmaf(d.y, w2s[(4 * (kq + 12) + 1) * 64 + f], h3);
            h3 = fmaf(d.z, w2s[(4 * (kq + 12) + 2) * 64 + f], h3);
            h3 = fmaf(d.w, w2s[(4 * (kq + 12) + 3) * 64 + f], h3);
        }
        float h = (h0 + h1) + (h2 + h3);
        acc += fmaxf(h, 0.f);
    }
    red[w][f] = acc;
    __syncthreads();
    if (t < 64) {
        float c = (float)(e - s);
        c = c > 1.f ? c : 1.f;
        float sum = 0.f;
#pragma unroll
        for (int j = 0; j < 8; ++j) sum += red[j][t];
        pooled[t] = sum / c;
    }
    __syncthreads();
    if (t < 32) {
        float sv = bf1[t];
#pragma unroll
        for (int k = 0; k < 64; ++k) sv += pooled[k] * wf1[k * 32 + t];
        gv[t] = fmaxf(sv, 0.f);
    }
    __syncthreads();
    if (t == 0) {
        float sv = bf2[0];
#pragma unroll
        for (int j = 0; j < 32; ++j) sv += gv[j] * wf2[j];
        out[g] = sv;
    }
}

extern "C" void kernel_launch(void* const* d_in, const int* in_sizes, int n_in,
                              void* d_out, int out_size, void* d_ws, size_t ws_size,
                              hipStream_t stream) {
    const float* x      = (const float*)d_in[0];
    const int*   ei     = (const int*)d_in[2];
    const int*   batch  = (const int*)d_in[3];
    const float* w_node = (const float*)d_in[4];
    const float* b_node = (const float*)d_in[5];
    const float* w1  = (const float*)d_in[8];
    const float* b1  = (const float*)d_in[9];
    const float* w2  = (const float*)d_in[10];
    const float* b2  = (const float*)d_in[11];
    const float* wf1 = (const float*)d_in[12];
    const float* bf1 = (const float*)d_in[13];
    const float* wf2 = (const float*)d_in[14];
    const float* bf2 = (const float*)d_in[15];
    float* out = (float*)d_out;

    const int N = in_sizes[0] / 2;  // 100000
    const int E = in_sizes[2] / 2;  // 3200000
    const int G = out_size;         // 1024
    const int NB = (N + 255) >> 8;  // 391

    auto align256 = [](size_t v) { return (v + 255) & ~(size_t)255; };
    char* ws = (char*)d_ws;
    size_t off = 0;
    float*  dis     = (float*)(ws + off);  off += align256((size_t)N * 4);
    int*    rowPtr  = (int*)(ws + off);    off += align256((size_t)(N + 1) * 4);
    int*    bcur    = (int*)(ws + off);    off += align256((size_t)NBMAX * 4);
    int*    srcIdx  = (int*)(ws + off);    off += align256((size_t)E * 4);
    float*  region1 = (float*)(ws + off);  off += align256((size_t)N * 64 * 4);  // pairBuf, then z2
    __half* hT1     = (__half*)(ws + off); off += align256((size_t)N * 64 * 2);  // h~1 [N,64] fp16
    float4* p       = (float4*)(ws + off); off += align256((size_t)N * 16);      // {x0,x1,dis,0}

    unsigned int* pairBuf = (unsigned int*)region1;  // 19.2 MB < 25.6 MB
    float* z2 = region1;                             // [N,64] fp32 (pairBuf dead by layer 2)

    const int B = 256;

    // bcur = per-bucket counters, zeroed each call (deterministic)
    hipMemsetAsync(bcur, 0, (size_t)NBMAX * 4, stream);
    {
        const int CHUNK = 256 * 32;                  // 8192 edges/block
        int nblk = (E + CHUNK - 1) / CHUNK;          // 391
        k_passA<<<nblk, B, 0, stream>>>(ei, bcur, pairBuf, E);
    }
    k_passB<<<NB, B, 0, stream>>>(bcur, pairBuf, rowPtr, dis, srcIdx, x, p, N, E);

    // layer 1: 2 nodes/wave, L2-resident p-gather + recompute + fused @w1 -> fp16 h~1
    {
        int nwaves = (N + 1) / 2;                     // 50000
        long long threads = (long long)nwaves * 64;
        int nblk = (int)((threads + B - 1) / B);      // 12500
        k_agg32x2<<<nblk, B, 0, stream>>>(rowPtr, srcIdx, p, w_node, b_node,
                                          w1, b1, hT1, N);
    }

    // layer 2: 2 nodes/wave, fp16 128B-row gather -> fp32 z2
    {
        int nwaves = (N + 1) / 2;                     // 50000
        long long threads = (long long)nwaves * 64;
        int nblk = (int)((threads + B - 1) / B);      // 12500
        k_agg64h2<<<nblk, B, 0, stream>>>(rowPtr, srcIdx, hT1, dis, z2, N);
    }

    // fused h2-compute + mean-pool + head (512 thr, w2 in LDS, 4-chain ILP)
    k_poolhead<<<G, 512, 0, stream>>>(z2, w2, b2, batch, wf1, bf1, wf2, bf2, out, N);
}

// Round 19
// 248.343 us; speedup vs baseline: 1.1924x; 1.1924x over previous
//
#include <hip/hip_runtime.h>
#include <hip/hip_fp16.h>

// ---------------------------------------------------------------------------
// GNN_20237885899323: 2-layer GCN + mean-pool + MLP head, fp32 compute.
// Round 19: byte-exact r16 (249.2us anchor) + ONE change: __launch_bounds__
// (256,4) on k_poolhead. r16's poolhead compiled at VGPR 48 -> its wcol[64]
// lived in L2-hot scratch (~200cy loads inside the FMA chain, VALU 17%).
// 4 blocks/CU bound -> VGPR cap 128 -> wcol in real VGPRs. r17/r18's 512-thr
// rewrites both spilled under the default cap (WRITE 15-28MB phantom scratch)
// and regressed; this is the single-variable version of the same intent.
// ---------------------------------------------------------------------------

#define NBMAX 512
#define BCAP 12288
#define CAPL 10240

// pass A: bin edges by dst>>8; entry = (dst&255)<<24 | src.
// bcur[b] is a running COUNT (zeroed before launch). 8192-edge chunks so each
// (block,bucket) burst is ~16 entries = one full 64B line, one writer/line.
__global__ void k_passA(const int* __restrict__ ei, int* __restrict__ bcur,
                        unsigned int* __restrict__ pairBuf, int E) {
    const int T = 256, EPT = 32, CHUNK = T * EPT;  // 8192 edges/block
    __shared__ int dLds[CHUNK];
    __shared__ int h[NBMAX];
    __shared__ int base[NBMAX];
    int chunk = blockIdx.x * CHUNK;
    int t = threadIdx.x;
    h[t] = 0; h[t + 256] = 0;
    __syncthreads();
    int nE = min(E - chunk, CHUNK);
    for (int i = t; i < nE; i += T) {
        int d = ei[E + chunk + i];
        dLds[i] = d;
        atomicAdd(&h[d >> 8], 1);
    }
    __syncthreads();
    for (int bb = t; bb < NBMAX; bb += T) {
        int c = h[bb];
        base[bb] = c > 0 ? atomicAdd(&bcur[bb], c) : 0;  // reserve [base, base+c)
        h[bb] = 0;  // becomes local cursor
    }
    __syncthreads();
    for (int i = t; i < nE; i += T) {
        int s = ei[chunk + i];
        int d = dLds[i];
        int bb = d >> 8;
        int pos = base[bb] + atomicAdd(&h[bb], 1);
        pairBuf[(size_t)bb * BCAP + pos] = ((unsigned int)(d & 255) << 24) | (unsigned int)s;
    }
}

// pass B: per-bucket counting sort -> rowPtr, dis, srcIdx, p={x0,x1,dis,0}
__global__ void k_passB(const int* __restrict__ bcur,
                        const unsigned int* __restrict__ pairBuf,
                        int* __restrict__ rowPtr, float* __restrict__ dis,
                        int* __restrict__ srcIdx, const float* __restrict__ x,
                        float4* __restrict__ p, int N, int E) {
    __shared__ unsigned int eLds[CAPL];
    __shared__ int hist[256];
    __shared__ int scan[256];
    int b = blockIdx.x;
    int t = threadIdx.x;  // 256
    int count = bcur[b];
    const unsigned int* src = pairBuf + (size_t)b * BCAP;
    // gbase = sum of bucket counts below b (redundant per-block reduce)
    int part = 0;
    for (int i = t; i < b; i += 256) part += bcur[i];
    scan[t] = part;
    __syncthreads();
    for (int o = 128; o > 0; o >>= 1) {
        if (t < o) scan[t] += scan[t + o];
        __syncthreads();
    }
    int gbase = scan[0];
    __syncthreads();
    hist[t] = 0;
    int nStage = min(count, CAPL);
    for (int i = t; i < nStage; i += 256) eLds[i] = __builtin_nontemporal_load(src + i);
    __syncthreads();
    for (int i = t; i < nStage; i += 256) atomicAdd(&hist[eLds[i] >> 24], 1);
    for (int i = CAPL + t; i < count; i += 256)
        atomicAdd(&hist[__builtin_nontemporal_load(src + i) >> 24], 1);
    __syncthreads();
    int c = hist[t];
    scan[t] = c;
    __syncthreads();
    for (int o = 1; o < 256; o <<= 1) {
        int v = (t >= o) ? scan[t - o] : 0;
        __syncthreads();
        scan[t] += v;
        __syncthreads();
    }
    int excl = scan[t] - c;
    int node = (b << 8) + t;
    float dval = rsqrtf((float)c + 1.0f);  // +1 self loop
    if (node < N) {
        rowPtr[node] = gbase + excl;
        dis[node] = dval;
        float4 pv;
        pv.x = x[2 * node]; pv.y = x[2 * node + 1]; pv.z = dval; pv.w = 0.f;
        p[node] = pv;
        if (node == N - 1) rowPtr[N] = E;
    }
    hist[t] = excl;
    __syncthreads();
    for (int i = t; i < nStage; i += 256) {
        unsigned int e = eLds[i];
        int pos = atomicAdd(&hist[e >> 24], 1);
        srcIdx[gbase + pos] = (int)(e & 0xFFFFFFu);  // cached: clustered, L2 merges
    }
    for (int i = CAPL + t; i < count; i += 256) {
        unsigned int e = __builtin_nontemporal_load(src + i);
        int pos = atomicAdd(&hist[e >> 24], 1);
        srcIdx[gbase + pos] = (int)(e & 0xFFFFFFu);
    }
}

// layer 1, TWO nodes per wave: gather p[src] (16B, L2-resident), recompute
// h~0 in-register; two independent chains; dual butterfly; fused @w1 -> fp16.
__global__ void k_agg32x2(const int* __restrict__ rowPtr, const int* __restrict__ srcIdx,
                          const float4* __restrict__ p, const float* __restrict__ wn,
                          const float* __restrict__ bn, const float* __restrict__ w1,
                          const float* __restrict__ bb1, __half* __restrict__ hOut, int N) {
    constexpr int RPI = 8, U = 4, CH = RPI * U;  // 32 slots per node per iter
    int wid = (blockIdx.x * blockDim.x + threadIdx.x) >> 6;
    int n0 = 2 * wid;
    if (n0 >= N) return;
    int n1 = n0 + 1;
    bool has1 = (n1 < N);
    int lane = threadIdx.x & 63;
    int q = lane & 7;   // feature quad: f = 4q..4q+3
    int r = lane >> 3;  // row group 0..7
    float w0c[4], w1c[4], bnv[4];
#pragma unroll
    for (int j = 0; j < 4; ++j) {
        w0c[j] = wn[4 * q + j];
        w1c[j] = wn[32 + 4 * q + j];
        bnv[j] = bn[4 * q + j];
    }
    float4 pd0 = p[n0];
    float4 pd1 = p[has1 ? n1 : n0];
    float a0[4] = {0.f, 0.f, 0.f, 0.f};
    float a1[4] = {0.f, 0.f, 0.f, 0.f};
    if (r == 0) {  // self loops
#pragma unroll
        for (int j = 0; j < 4; ++j) {
            float v0 = fmaf(pd0.x, w0c[j], fmaf(pd0.y, w1c[j], bnv[j]));
            a0[j] = fmaxf(v0, 0.f) * pd0.z;
            float v1 = fmaf(pd1.x, w0c[j], fmaf(pd1.y, w1c[j], bnv[j]));
            a1[j] = has1 ? fmaxf(v1, 0.f) * pd1.z : 0.f;
        }
    }
    // adjacent segments: 3 rowPtr loads cover both
    int b0 = rowPtr[n0];
    int e0 = rowPtr[n0 + 1];
    int e1 = has1 ? rowPtr[n0 + 2] : e0;
    int beg1 = e0;
    for (int base0 = b0, base1 = beg1; base0 < e0 || base1 < e1;
         base0 += CH, base1 += CH) {
        int s0[U], s1[U];
        float m0[U], m1[U];
#pragma unroll
        for (int u = 0; u < U; ++u) {
            int i0 = base0 + r + u * RPI;
            m0[u] = (i0 < e0) ? 1.f : 0.f;
            s0[u] = __builtin_nontemporal_load(srcIdx + ((e0 > b0) ? min(i0, e0 - 1) : 0));
            int i1 = base1 + r + u * RPI;
            m1[u] = (i1 < e1) ? 1.f : 0.f;
            s1[u] = __builtin_nontemporal_load(srcIdx + ((e1 > beg1) ? min(i1, e1 - 1) : 0));
        }
        float4 ps0[U], ps1[U];
#pragma unroll
        for (int u = 0; u < U; ++u) ps0[u] = p[s0[u]];
#pragma unroll
        for (int u = 0; u < U; ++u) ps1[u] = p[s1[u]];
#pragma unroll
        for (int u = 0; u < U; ++u) {
            float sc0 = ps0[u].z * m0[u];
            float sc1 = ps1[u].z * m1[u];
#pragma unroll
            for (int j = 0; j < 4; ++j) {
                float v0 = fmaf(ps0[u].x, w0c[j], fmaf(ps0[u].y, w1c[j], bnv[j]));
                a0[j] = fmaf(fmaxf(v0, 0.f), sc0, a0[j]);
                float v1 = fmaf(ps1[u].x, w0c[j], fmaf(ps1[u].y, w1c[j], bnv[j]));
                a1[j] = fmaf(fmaxf(v1, 0.f), sc1, a1[j]);
            }
        }
    }
    // dual butterfly reduce across row groups (two independent chains)
#pragma unroll
    for (int mk = 8; mk < 64; mk <<= 1) {
#pragma unroll
        for (int j = 0; j < 4; ++j) {
            a0[j] += __shfl_xor(a0[j], mk);
            a1[j] += __shfl_xor(a1[j], mk);
        }
    }
    // fused @w1 for both nodes; w1 column loaded once, reused
    int f = lane;
    float s0v = 0.f, s1v = 0.f;
#pragma unroll
    for (int q2 = 0; q2 < 8; ++q2) {
#pragma unroll
        for (int j = 0; j < 4; ++j) {
            float wv = w1[(4 * q2 + j) * 64 + f];
            s0v = fmaf(__shfl(a0[j], q2), wv, s0v);
            s1v = fmaf(__shfl(a1[j], q2), wv, s1v);
        }
    }
    float bias = bb1[f];
    float h0 = fmaxf(fmaf(pd0.z, s0v, bias), 0.f) * pd0.z;
    hOut[(size_t)n0 * 64 + f] = __float2half(h0);
    if (has1) {
        float h1 = fmaxf(fmaf(pd1.z, s1v, bias), 0.f) * pd1.z;
        hOut[(size_t)n1 * 64 + f] = __float2half(h1);
    }
}

// layer 2, TWO nodes per wave: fp16 128B-row gather, two independent chains
// (U=2 each), dual butterfly, both fp32 z-rows stored.
__global__ void k_agg64h2(const int* __restrict__ rowPtr, const int* __restrict__ srcIdx,
                          const __half* __restrict__ y, const float* __restrict__ dis,
                          float* __restrict__ z, int N) {
    constexpr int RPI = 8, U = 2, CH = RPI * U;  // 16 slots per node per iter
    int wid = (blockIdx.x * blockDim.x + threadIdx.x) >> 6;
    int n0 = 2 * wid;
    if (n0 >= N) return;
    int n1 = n0 + 1;
    bool has1 = (n1 < N);
    int lane = threadIdx.x & 63;
    int q = lane & 7;   // 16-byte chunk: features 8q..8q+7
    int r = lane >> 3;  // row group 0..7
    const float4* yq = (const float4*)y;  // one row = 8 float4 (64 halves)
    float acc0[8] = {0.f, 0.f, 0.f, 0.f, 0.f, 0.f, 0.f, 0.f};
    float acc1[8] = {0.f, 0.f, 0.f, 0.f, 0.f, 0.f, 0.f, 0.f};
    if (r == 0) {  // self rows
        float4 a = yq[(size_t)n0 * 8 + q];
        union { float4 f4; __half2 h2[4]; } cv; cv.f4 = a;
#pragma unroll
        for (int j = 0; j < 4; ++j) {
            float2 f = __half22float2(cv.h2[j]);
            acc0[2 * j] = f.x; acc0[2 * j + 1] = f.y;
        }
        if (has1) {
            float4 b = yq[(size_t)n1 * 8 + q];
            union { float4 f4; __half2 h2[4]; } cw; cw.f4 = b;
#pragma unroll
            for (int j = 0; j < 4; ++j) {
                float2 f = __half22float2(cw.h2[j]);
                acc1[2 * j] = f.x; acc1[2 * j + 1] = f.y;
            }
        }
    }
    int b0 = rowPtr[n0];
    int e0 = rowPtr[n0 + 1];
    int e1 = has1 ? rowPtr[n0 + 2] : e0;
    int beg1 = e0;
    for (int base0 = b0, base1 = beg1; base0 < e0 || base1 < e1;
         base0 += CH, base1 += CH) {
        int s0[U], s1[U];
        float m0[U], m1[U];
#pragma unroll
        for (int u = 0; u < U; ++u) {
            int i0 = base0 + r + u * RPI;
            m0[u] = (i0 < e0) ? 1.f : 0.f;
            s0[u] = __builtin_nontemporal_load(srcIdx + ((e0 > b0) ? min(i0, e0 - 1) : 0));
            int i1 = base1 + r + u * RPI;
            m1[u] = (i1 < e1) ? 1.f : 0.f;
            s1[u] = __builtin_nontemporal_load(srcIdx + ((e1 > beg1) ? min(i1, e1 - 1) : 0));
        }
#pragma unroll
        for (int u = 0; u < U; ++u) {
            float4 a = yq[(size_t)s0[u] * 8 + q];
            float4 b = yq[(size_t)s1[u] * 8 + q];
            union { float4 f4; __half2 h2[4]; } ca; ca.f4 = a;
            union { float4 f4; __half2 h2[4]; } cb; cb.f4 = b;
#pragma unroll
            for (int j = 0; j < 4; ++j) {
                float2 fa = __half22float2(ca.h2[j]);
                acc0[2 * j]     = fmaf(fa.x, m0[u], acc0[2 * j]);
                acc0[2 * j + 1] = fmaf(fa.y, m0[u], acc0[2 * j + 1]);
                float2 fb = __half22float2(cb.h2[j]);
                acc1[2 * j]     = fmaf(fb.x, m1[u], acc1[2 * j]);
                acc1[2 * j + 1] = fmaf(fb.y, m1[u], acc1[2 * j + 1]);
            }
        }
    }
    // dual butterfly reduce across the 8 row groups
#pragma unroll
    for (int mk = 8; mk < 64; mk <<= 1) {
#pragma unroll
        for (int j = 0; j < 8; ++j) {
            acc0[j] += __shfl_xor(acc0[j], mk);
            acc1[j] += __shfl_xor(acc1[j], mk);
        }
    }
    if (r == 0) {
        float dv0 = dis[n0];
        float4 o0 = {acc0[0] * dv0, acc0[1] * dv0, acc0[2] * dv0, acc0[3] * dv0};
        float4 o1 = {acc0[4] * dv0, acc0[5] * dv0, acc0[6] * dv0, acc0[7] * dv0};
        float4* zp0 = (float4*)(z + (size_t)n0 * 64 + q * 8);
        zp0[0] = o0;  // plain store: stays in L2 for poolhead
        zp0[1] = o1;
        if (has1) {
            float dv1 = dis[n1];
            float4 o2 = {acc1[0] * dv1, acc1[1] * dv1, acc1[2] * dv1, acc1[3] * dv1};
            float4 o3 = {acc1[4] * dv1, acc1[5] * dv1, acc1[6] * dv1, acc1[7] * dv1};
            float4* zp1 = (float4*)(z + (size_t)n1 * 64 + q * 8);
            zp1[0] = o2;
            zp1[1] = o3;
        }
    }
}

// block-per-graph (256 thr): binary-search node range in sorted batch;
// h2 = relu(z2@w2+b2) on the fly (w2 column in VGPRs -- launch_bounds(256,4)
// raises the VGPR cap to 128 so wcol[64] actually lives in registers instead
// of L2-scratch); mean; MLP head.
__global__ void __launch_bounds__(256, 4)
k_poolhead(const float* __restrict__ z2, const float* __restrict__ w2,
           const float* __restrict__ b2, const int* __restrict__ batch,
           const float* __restrict__ wf1, const float* __restrict__ bf1,
           const float* __restrict__ wf2, const float* __restrict__ bf2,
           float* __restrict__ out, int N) {
    __shared__ float red[4][64];
    __shared__ float pooled[64];
    __shared__ float gv[32];
    __shared__ int range[2];
    int g = blockIdx.x;
    int t = threadIdx.x;  // 256
    if (t < 2) {
        int target = g + t;
        int lo = 0, hi = N;
        while (lo < hi) {
            int mid = (lo + hi) >> 1;
            if (batch[mid] < target) lo = mid + 1; else hi = mid;
        }
        range[t] = lo;
    }
    __syncthreads();
    int s = range[0], e = range[1];
    int w = t >> 6, f = t & 63;
    float wcol[64];
#pragma unroll
    for (int k = 0; k < 64; ++k) wcol[k] = w2[k * 64 + f];
    float bf = b2[f];
    float acc = 0.f;
    for (int n = s + w; n < e; n += 4) {
        const float4* zr = (const float4*)(z2 + (size_t)n * 64);
        float h = bf;
#pragma unroll
        for (int kq = 0; kq < 16; ++kq) {
            float4 zv = zr[kq];
            h += zv.x * wcol[4 * kq + 0];
            h += zv.y * wcol[4 * kq + 1];
            h += zv.z * wcol[4 * kq + 2];
            h += zv.w * wcol[4 * kq + 3];
        }
        acc += fmaxf(h, 0.f);
    }
    red[w][f] = acc;
    __syncthreads();
    if (t < 64) {
        float c = (float)(e - s);
        c = c > 1.f ? c : 1.f;
        pooled[t] = (red[0][t] + red[1][t] + red[2][t] + red[3][t]) / c;
    }
    __syncthreads();
    if (t < 32) {
        float sv = bf1[t];
#pragma unroll
        for (int k = 0; k < 64; ++k) sv += pooled[k] * wf1[k * 32 + t];
        gv[t] = fmaxf(sv, 0.f);
    }
    __syncthreads();
    if (t == 0) {
        float sv = bf2[0];
#pragma unroll
        for (int j = 0; j < 32; ++j) sv += gv[j] * wf2[j];
        out[g] = sv;
    }
}

extern "C" void kernel_launch(void* const* d_in, const int* in_sizes, int n_in,
                              void* d_out, int out_size, void* d_ws, size_t ws_size,
                              hipStream_t stream) {
    const float* x      = (const float*)d_in[0];
    const int*   ei     = (const int*)d_in[2];
    const int*   batch  = (const int*)d_in[3];
    const float* w_node = (const float*)d_in[4];
    const float* b_node = (const float*)d_in[5];
    const float* w1  = (const float*)d_in[8];
    const float* b1  = (const float*)d_in[9];
    const float* w2  = (const float*)d_in[10];
    const float* b2  = (const float*)d_in[11];
    const float* wf1 = (const float*)d_in[12];
    const float* bf1 = (const float*)d_in[13];
    const float* wf2 = (const float*)d_in[14];
    const float* bf2 = (const float*)d_in[15];
    float* out = (float*)d_out;

    const int N = in_sizes[0] / 2;  // 100000
    const int E = in_sizes[2] / 2;  // 3200000
    const int G = out_size;         // 1024
    const int NB = (N + 255) >> 8;  // 391

    auto align256 = [](size_t v) { return (v + 255) & ~(size_t)255; };
    char* ws = (char*)d_ws;
    size_t off = 0;
    float*  dis     = (float*)(ws + off);  off += align256((size_t)N * 4);
    int*    rowPtr  = (int*)(ws + off);    off += align256((size_t)(N + 1) * 4);
    int*    bcur    = (int*)(ws + off);    off += align256((size_t)NBMAX * 4);
    int*    srcIdx  = (int*)(ws + off);    off += align256((size_t)E * 4);
    float*  region1 = (float*)(ws + off);  off += align256((size_t)N * 64 * 4);  // pairBuf, then z2
    __half* hT1     = (__half*)(ws + off); off += align256((size_t)N * 64 * 2);  // h~1 [N,64] fp16
    float4* p       = (float4*)(ws + off); off += align256((size_t)N * 16);      // {x0,x1,dis,0}

    unsigned int* pairBuf = (unsigned int*)region1;  // 19.2 MB < 25.6 MB
    float* z2 = region1;                             // [N,64] fp32 (pairBuf dead by layer 2)

    const int B = 256;

    // bcur = per-bucket counters, zeroed each call (deterministic)
    hipMemsetAsync(bcur, 0, (size_t)NBMAX * 4, stream);
    {
        const int CHUNK = 256 * 32;                  // 8192 edges/block
        int nblk = (E + CHUNK - 1) / CHUNK;          // 391
        k_passA<<<nblk, B, 0, stream>>>(ei, bcur, pairBuf, E);
    }
    k_passB<<<NB, B, 0, stream>>>(bcur, pairBuf, rowPtr, dis, srcIdx, x, p, N, E);

    // layer 1: 2 nodes/wave, L2-resident p-gather + recompute + fused @w1 -> fp16 h~1
    {
        int nwaves = (N + 1) / 2;                     // 50000
        long long threads = (long long)nwaves * 64;
        int nblk = (int)((threads + B - 1) / B);      // 12500
        k_agg32x2<<<nblk, B, 0, stream>>>(rowPtr, srcIdx, p, w_node, b_node,
                                          w1, b1, hT1, N);
    }

    // layer 2: 2 nodes/wave, fp16 128B-row gather -> fp32 z2
    {
        int nwaves = (N + 1) / 2;                     // 50000
        long long threads = (long long)nwaves * 64;
        int nblk = (int)((threads + B - 1) / B);      // 12500
        k_agg64h2<<<nblk, B, 0, stream>>>(rowPtr, srcIdx, hT1, dis, z2, N);
    }

    // fused h2-compute + mean-pool + head (256 thr, wcol in true VGPRs)
    k_poolhead<<<G, B, 0, stream>>>(z2, w2, b2, batch, wf1, bf1, wf2, bf2, out, N);
}